// Round 1
// baseline (987.901 us; speedup 1.0000x reference)
//
#include <hip/hip_runtime.h>

#define D_ 768
#define B_ 2048
#define NDOM 9
#define NTOT 10
#define MT 128
#define NT 128
#define KT 32
#define LDK 40     // padded LDS leading dim (fp16 elems): 80B row stride, conflict-benign
#define NTILES 6   // 768 / 128

typedef _Float16 f16;
typedef _Float16 f16x8 __attribute__((ext_vector_type(8)));
typedef _Float16 f16x4 __attribute__((ext_vector_type(4)));
typedef float f32x4 __attribute__((ext_vector_type(4)));

// ---------------------------------------------------------------- bucket ----
__global__ __launch_bounds__(256) void bucket_kernel(const int* cat32, int* perm,
                                                     int* off, int* cnt, int* dom) {
  __shared__ int scnt[NDOM], soff[NDOM], scur[NDOM];
  __shared__ int odd_nz;
  int t = threadIdx.x;
  if (t == 0) odd_nz = 0;
  if (t < NDOM) scnt[t] = 0;
  __syncthreads();
  // int32 vs int64 category detection: if the buffer is int64, every odd int32
  // word (high half, values in [0,9)) is zero. For int32 data that is ~impossible.
  int loc = 0;
  for (int i = t; i < B_; i += 256)
    if ((i & 1) && cat32[i] != 0) loc = 1;
  if (loc) atomicOr(&odd_nz, 1);
  __syncthreads();
  int strd = odd_nz ? 1 : 2;
  for (int i = t; i < B_; i += 256) atomicAdd(&scnt[cat32[i * strd]], 1);
  __syncthreads();
  if (t == 0) { int a = 0; for (int n = 0; n < NDOM; n++) { soff[n] = a; a += scnt[n]; } }
  __syncthreads();
  if (t < NDOM) { scur[t] = soff[t]; off[t] = soff[t]; cnt[t] = scnt[t]; }
  __syncthreads();
  for (int i = t; i < B_; i += 256) {
    int n = cat32[i * strd];
    int pos = atomicAdd(&scur[n], 1);
    perm[pos] = i;
    dom[pos] = n;
  }
}

// ---------------------------------------------------------------- layer 1 ---
struct L1P {
  const float* x[2];
  const float* W1[2]; const float* b1[2];
  const float* sW1[2]; const float* sb1[2];
  const float* gW1[2]; const float* gb1[2];
  const float* demb;
  const int* perm; const int* off; const int* cnt;
  f16* h;
};

__global__ __launch_bounds__(256) void layer1_kernel(L1P p) {
  const int z = blockIdx.z;
  const int g = blockIdx.y;
  const int mt = blockIdx.x / NTILES;
  const int nt = blockIdx.x % NTILES;

  int row_off, row_cnt, slot, gdom = 0;
  const float* Wp; const float* bias;
  bool isGate = false;
  if (g < 54) {                       // domain experts
    int n = g / 6, e = g % 6;
    row_off = p.off[n]; row_cnt = p.cnt[n];
    Wp = p.W1[z] + (size_t)(n * 6 + e) * D_ * D_;
    bias = p.b1[z] + (n * 6 + e) * D_;
    slot = e;
  } else if (g < 58) {                // shared experts
    int e = g - 54;
    row_off = 0; row_cnt = B_;
    Wp = p.sW1[z] + (size_t)e * D_ * D_;
    bias = p.sb1[z] + e * D_;
    slot = 6 + e;
  } else {                            // gate hidden (K=1536: demb part broadcast)
    int n = g - 58;
    row_off = p.off[n]; row_cnt = p.cnt[n];
    Wp = p.gW1[z] + (size_t)n * 2 * D_ * D_;
    bias = p.gb1[z] + n * D_;
    slot = 10; isGate = true; gdom = n;
  }
  if (mt * MT >= row_cnt) return;

  __shared__ f16 As[MT][LDK];
  __shared__ f16 Bs[NT][LDK];

  const int t = threadIdx.x;
  const int wave = t >> 6, lane = t & 63;
  const int wr = (wave >> 1) * 64, wc = (wave & 1) * 64;
  const int r0 = lane & 15, q = lane >> 4;
  const int jbase = nt * NT;

  const int ar = t >> 1;              // A staging: row
  const int akq = (t & 1) * 16;       // A staging: k chunk
  const int bj = (t >> 3) * 4;        // B staging: col
  const int bk = (t & 7) * 4;         // B staging: k

  const bool rowok = (mt * MT + ar) < row_cnt;
  const float* arow = p.x[z] + (size_t)(rowok ? p.perm[row_off + mt * MT + ar] : 0) * D_;
  const float* dembn = p.demb + (size_t)gdom * D_;

  f32x4 acc[4][4];
#pragma unroll
  for (int a = 0; a < 4; a++)
#pragma unroll
    for (int b = 0; b < 4; b++) acc[a][b] = (f32x4){0.f, 0.f, 0.f, 0.f};

  const int kiters = isGate ? 2 * (D_ / KT) : (D_ / KT);
  for (int kk = 0; kk < kiters; kk++) {
    const int k0 = kk * KT;
    const float* ap; int ac;
    if (isGate) { if (k0 < D_) { ap = dembn; ac = k0; } else { ap = arow; ac = k0 - D_; } }
    else { ap = arow; ac = k0; }
    f32x4 av[4];
#pragma unroll
    for (int i = 0; i < 4; i++) av[i] = *(const f32x4*)(ap + ac + akq + i * 4);
    f32x4 wv[4];
#pragma unroll
    for (int i = 0; i < 4; i++) wv[i] = *(const f32x4*)(Wp + (size_t)(k0 + bk + i) * D_ + jbase + bj);

    __syncthreads();                  // previous iteration's compute done
    f16 atmp[16];
#pragma unroll
    for (int i = 0; i < 4; i++) {
      atmp[4 * i + 0] = (f16)av[i][0]; atmp[4 * i + 1] = (f16)av[i][1];
      atmp[4 * i + 2] = (f16)av[i][2]; atmp[4 * i + 3] = (f16)av[i][3];
    }
    *(f16x8*)&As[ar][akq] = *(f16x8*)&atmp[0];
    *(f16x8*)&As[ar][akq + 8] = *(f16x8*)&atmp[8];
#pragma unroll
    for (int j = 0; j < 4; j++) {     // transpose W into Bs[col][k]
      f16x4 c = { (f16)wv[0][j], (f16)wv[1][j], (f16)wv[2][j], (f16)wv[3][j] };
      *(f16x4*)&Bs[bj + j][bk] = c;
    }
    __syncthreads();

    f16x8 af[4], bf[4];
#pragma unroll
    for (int m = 0; m < 4; m++) af[m] = *(const f16x8*)&As[wr + m * 16 + r0][q * 8];
#pragma unroll
    for (int nn = 0; nn < 4; nn++) bf[nn] = *(const f16x8*)&Bs[wc + nn * 16 + r0][q * 8];
#pragma unroll
    for (int m = 0; m < 4; m++)
#pragma unroll
      for (int nn = 0; nn < 4; nn++)
        acc[m][nn] = __builtin_amdgcn_mfma_f32_16x16x32_f16(af[m], bf[nn], acc[m][nn], 0, 0, 0);
  }

  f16* hout = p.h + (size_t)(z * 11 + slot) * B_ * D_;
#pragma unroll
  for (int nn = 0; nn < 4; nn++) {
    const int col = jbase + wc + nn * 16 + r0;
    const float bc = bias[col];
#pragma unroll
    for (int m = 0; m < 4; m++) {
#pragma unroll
      for (int i = 0; i < 4; i++) {
        int lr = mt * MT + wr + m * 16 + q * 4 + i;
        if (lr < row_cnt) {
          float v = acc[m][nn][i] + bc;
          v = v / (1.f + __expf(-v));                  // SiLU
          hout[(size_t)(row_off + lr) * D_ + col] = (f16)v;
        }
      }
    }
  }
}

// ---------------------------------------------------------------- gate ------
struct GP {
  const f16* h;
  const float* gW2[2]; const float* gb2[2]; const float* temp[2];
  const int* dom;
  float* gates;
};

__global__ __launch_bounds__(256) void gate_kernel(GP p) {
  int wid = (blockIdx.x * 256 + threadIdx.x) >> 6;
  int lane = threadIdx.x & 63;
  int z = wid >> 11;
  int pos = wid & (B_ - 1);
  int n = p.dom[pos];
  const f16* gh = p.h + ((size_t)(z * 11 + 10) * B_ + pos) * D_;
  const float* W = p.gW2[z] + (size_t)n * D_ * NTOT;
  float part[NTOT];
#pragma unroll
  for (int e = 0; e < NTOT; e++) part[e] = 0.f;
  for (int k = lane; k < D_; k += 64) {
    float a = (float)gh[k];
    const float* wrow = W + (size_t)k * NTOT;
#pragma unroll
    for (int e = 0; e < NTOT; e++) part[e] = fmaf(a, wrow[e], part[e]);
  }
#pragma unroll
  for (int e = 0; e < NTOT; e++) {
    float v = part[e];
#pragma unroll
    for (int s = 32; s > 0; s >>= 1) v += __shfl_xor(v, s, 64);
    part[e] = v;
  }
  float tv = p.temp[z][n];
  float tq = (tv > 15.f ? tv : log1pf(__expf(tv))) + 1e-4f;   // softplus + eps
  const float* b2 = p.gb2[z] + n * NTOT;
  float mx = -1e30f;
#pragma unroll
  for (int e = 0; e < NTOT; e++) { part[e] = (part[e] + b2[e]) / tq; mx = fmaxf(mx, part[e]); }
  float s = 0.f;
#pragma unroll
  for (int e = 0; e < NTOT; e++) { part[e] = __expf(part[e] - mx); s += part[e]; }
  float inv = 1.f / s;
  if (lane < NTOT) p.gates[((size_t)z * B_ + pos) * NTOT + lane] = part[lane] * inv;
}

// ---------------------------------------------------------------- layer 2 ---
struct L2P {
  const f16* h;
  const float* W2[2]; const float* b2[2];
  const float* sW2[2]; const float* sb2[2];
  const float* gates;
  const int* perm; const int* off; const int* cnt;
  float* out;
};

__global__ __launch_bounds__(256) void layer2_kernel(L2P p) {
  const int zz = blockIdx.z;
  const int z = zz >> 1, es = zz & 1;      // branch, expert-half
  const int n = blockIdx.y;
  const int mt = blockIdx.x / NTILES, nt = blockIdx.x % NTILES;
  const int row_off = p.off[n], row_cnt = p.cnt[n];
  if (mt * MT >= row_cnt) return;
  const int ebase = es * 5;

  __shared__ f16 As[MT][LDK];
  __shared__ f16 Bs[NT][LDK];
  __shared__ float sg[MT][NTOT];
  __shared__ int sperm[MT];

  const int t = threadIdx.x;
  for (int i = t; i < MT * NTOT; i += 256) {
    int rr = i / NTOT, e = i % NTOT;
    int gp = row_off + mt * MT + rr;
    sg[rr][e] = (gp < B_) ? p.gates[((size_t)z * B_ + gp) * NTOT + e] : 0.f;
  }
  for (int i = t; i < MT; i += 256) {
    int gp = row_off + mt * MT + i;
    sperm[i] = (gp < B_) ? p.perm[gp] : 0;
  }
  __syncthreads();

  const int wave = t >> 6, lane = t & 63;
  const int wr = (wave >> 1) * 64, wc = (wave & 1) * 64;
  const int r0 = lane & 15, q = lane >> 4;
  const int jbase = nt * NT;
  const int ar = t >> 1, akq = (t & 1) * 16;
  const int bj = (t >> 3) * 4, bk = (t & 7) * 4;

  int posr = row_off + mt * MT + ar;
  if (posr >= B_) posr = B_ - 1;           // clamp; results masked at store

  f32x4 acc[4][4];
#pragma unroll
  for (int a = 0; a < 4; a++)
#pragma unroll
    for (int b = 0; b < 4; b++) acc[a][b] = (f32x4){0.f, 0.f, 0.f, 0.f};

  const float* pb[5];
#pragma unroll
  for (int ei = 0; ei < 5; ei++) {
    int e = ebase + ei;
    pb[ei] = (e < 6) ? (p.b2[z] + (size_t)(n * 6 + e) * D_)
                     : (p.sb2[z] + (size_t)(e - 6) * D_);
  }

  for (int ei = 0; ei < 5; ei++) {
    const int e = ebase + ei;
    const float* Wp = (e < 6) ? (p.W2[z] + (size_t)(n * 6 + e) * D_ * D_)
                              : (p.sW2[z] + (size_t)(e - 6) * D_ * D_);
    const f16* hrow = p.h + ((size_t)(z * 11 + e) * B_ + posr) * D_;
    const f16 gs = (f16)sg[ar][e];
    for (int kk = 0; kk < D_ / KT; kk++) {
      const int k0 = kk * KT;
      f16x8 v0 = *(const f16x8*)(hrow + k0 + akq);
      f16x8 v1 = *(const f16x8*)(hrow + k0 + akq + 8);
      f32x4 wv[4];
#pragma unroll
      for (int i = 0; i < 4; i++) wv[i] = *(const f32x4*)(Wp + (size_t)(k0 + bk + i) * D_ + jbase + bj);
      v0 *= gs; v1 *= gs;                  // fold gate into A operand
      __syncthreads();
      *(f16x8*)&As[ar][akq] = v0;
      *(f16x8*)&As[ar][akq + 8] = v1;
#pragma unroll
      for (int j = 0; j < 4; j++) {
        f16x4 c = { (f16)wv[0][j], (f16)wv[1][j], (f16)wv[2][j], (f16)wv[3][j] };
        *(f16x4*)&Bs[bj + j][bk] = c;
      }
      __syncthreads();
      f16x8 af[4], bf[4];
#pragma unroll
      for (int m = 0; m < 4; m++) af[m] = *(const f16x8*)&As[wr + m * 16 + r0][q * 8];
#pragma unroll
      for (int nn = 0; nn < 4; nn++) bf[nn] = *(const f16x8*)&Bs[wc + nn * 16 + r0][q * 8];
#pragma unroll
      for (int m = 0; m < 4; m++)
#pragma unroll
        for (int nn = 0; nn < 4; nn++)
          acc[m][nn] = __builtin_amdgcn_mfma_f32_16x16x32_f16(af[m], bf[nn], acc[m][nn], 0, 0, 0);
    }
  }

  const int zoff = z * D_;
#pragma unroll
  for (int nn = 0; nn < 4; nn++) {
    const int col = jbase + wc + nn * 16 + r0;
    float pbc[5];
#pragma unroll
    for (int ei = 0; ei < 5; ei++) pbc[ei] = pb[ei][col];
#pragma unroll
    for (int m = 0; m < 4; m++) {
#pragma unroll
      for (int i = 0; i < 4; i++) {
        const int lrt = wr + m * 16 + q * 4 + i;
        if (mt * MT + lrt < row_cnt) {
          float v = acc[m][nn][i];
#pragma unroll
          for (int ei = 0; ei < 5; ei++) v = fmaf(sg[lrt][ebase + ei], pbc[ei], v);
          float* dst = p.out + (size_t)sperm[lrt] * (2 * D_) + zoff + col;
          __hip_atomic_fetch_add(dst, v, __ATOMIC_RELAXED, __HIP_MEMORY_SCOPE_AGENT);
        }
      }
    }
  }
}

// ---------------------------------------------------------------- launch ----
extern "C" void kernel_launch(void* const* d_in, const int* in_sizes, int n_in,
                              void* d_out, int out_size, void* d_ws, size_t ws_size,
                              hipStream_t stream) {
  const float* content = (const float*)d_in[0];
  const float* ftr     = (const float*)d_in[1];
  const int*   cat     = (const int*)d_in[2];
  const float* demb    = (const float*)d_in[3];

  const float* cW1  = (const float*)d_in[4];
  const float* cb1  = (const float*)d_in[5];
  const float* cW2  = (const float*)d_in[6];
  const float* cb2  = (const float*)d_in[7];
  const float* csW1 = (const float*)d_in[8];
  const float* csb1 = (const float*)d_in[9];
  const float* csW2 = (const float*)d_in[10];
  const float* csb2 = (const float*)d_in[11];
  const float* cgW1 = (const float*)d_in[12];
  const float* cgb1 = (const float*)d_in[13];
  const float* cgW2 = (const float*)d_in[14];
  const float* cgb2 = (const float*)d_in[15];
  const float* ctemp= (const float*)d_in[16];

  const float* fW1  = (const float*)d_in[17];
  const float* fb1  = (const float*)d_in[18];
  const float* fW2  = (const float*)d_in[19];
  const float* fb2  = (const float*)d_in[20];
  const float* fsW1 = (const float*)d_in[21];
  const float* fsb1 = (const float*)d_in[22];
  const float* fsW2 = (const float*)d_in[23];
  const float* fsb2 = (const float*)d_in[24];
  const float* fgW1 = (const float*)d_in[25];
  const float* fgb1 = (const float*)d_in[26];
  const float* fgW2 = (const float*)d_in[27];
  const float* fgb2 = (const float*)d_in[28];
  const float* ftemp= (const float*)d_in[29];

  char* wsb = (char*)d_ws;
  int* perm   = (int*)wsb;               // 2048 ints
  int* off    = (int*)(wsb + 8192);      // 16 ints
  int* cnt    = (int*)(wsb + 8256);      // 16 ints
  int* dom    = (int*)(wsb + 8320);      // 2048 ints
  float* gates= (float*)(wsb + 16512);   // 2*2048*10 f32
  f16* h      = (f16*)(wsb + 180352);    // 2*11*2048*768 f16 (~66 MiB)
  float* out  = (float*)d_out;

  hipMemsetAsync(d_out, 0, (size_t)out_size * sizeof(float), stream);

  bucket_kernel<<<1, 256, 0, stream>>>(cat, perm, off, cnt, dom);

  L1P p1;
  p1.x[0] = content; p1.x[1] = ftr;
  p1.W1[0] = cW1;  p1.W1[1] = fW1;  p1.b1[0] = cb1;  p1.b1[1] = fb1;
  p1.sW1[0] = csW1; p1.sW1[1] = fsW1; p1.sb1[0] = csb1; p1.sb1[1] = fsb1;
  p1.gW1[0] = cgW1; p1.gW1[1] = fgW1; p1.gb1[0] = cgb1; p1.gb1[1] = fgb1;
  p1.demb = demb; p1.perm = perm; p1.off = off; p1.cnt = cnt; p1.h = h;
  layer1_kernel<<<dim3(16 * NTILES, 67, 2), 256, 0, stream>>>(p1);

  GP pg;
  pg.h = h; pg.gW2[0] = cgW2; pg.gW2[1] = fgW2;
  pg.gb2[0] = cgb2; pg.gb2[1] = fgb2;
  pg.temp[0] = ctemp; pg.temp[1] = ftemp;
  pg.dom = dom; pg.gates = gates;
  gate_kernel<<<dim3((2 * B_) / 4), 256, 0, stream>>>(pg);

  L2P p2;
  p2.h = h;
  p2.W2[0] = cW2;  p2.W2[1] = fW2;  p2.b2[0] = cb2;  p2.b2[1] = fb2;
  p2.sW2[0] = csW2; p2.sW2[1] = fsW2; p2.sb2[0] = csb2; p2.sb2[1] = fsb2;
  p2.gates = gates; p2.perm = perm; p2.off = off; p2.cnt = cnt; p2.out = out;
  layer2_kernel<<<dim3(16 * NTILES, 9, 4), 256, 0, stream>>>(p2);

  (void)in_sizes; (void)n_in; (void)ws_size;
}